// Round 2
// baseline (9898.176 us; speedup 1.0000x reference)
//
#include <hip/hip_runtime.h>
#include <hip/hip_bf16.h>
#include <math.h>

// Problem constants (B, L, V, E, H, M, P)
#define CB 2
#define CL 2048
#define CV 32000
#define CE 512
#define CH 1024
#define CM 256
#define CP 4096
#define CBL (CB*CL)     // 4096 rows
#define CH3 (3*CH)      // 3072
#define CE4 (4*CE)      // 2048

typedef __bf16 bf16x8 __attribute__((ext_vector_type(8)));
typedef float  f32x4  __attribute__((ext_vector_type(4)));
typedef unsigned short bfraw;
typedef unsigned int   u32;
typedef unsigned long long u64;

__device__ __forceinline__ bfraw f2bf(float f) {
  u32 u = __float_as_uint(f);
  u = (u + 0x7fffu + ((u >> 16) & 1u)) >> 16;   // RNE
  return (bfraw)u;
}

// ---------------- prep kernels ----------------
__global__ void k_cvt_bf16(const float* __restrict__ s, bfraw* __restrict__ d, int n4) {
  int i = blockIdx.x * 256 + threadIdx.x;
  if (i >= n4) return;
  f32x4 v = ((const f32x4*)s)[i];
  u32 lo = (u32)f2bf(v[0]) | ((u32)f2bf(v[1]) << 16);
  u32 hi = (u32)f2bf(v[2]) | ((u32)f2bf(v[3]) << 16);
  ((uint2*)d)[i] = make_uint2(lo, hi);
}

__global__ void k_gather_x(const float* __restrict__ emb, const int* __restrict__ ids,
                           bfraw* __restrict__ xbf) {
  int i = blockIdx.x * 256 + threadIdx.x;     // over CBL*CE/4 = 524288
  int m = i >> 7;                             // CE/4 = 128 float4 per row
  int c = i & 127;
  long src = (long)ids[m] * CE + c * 4;
  f32x4 v = *(const f32x4*)(emb + src);
  u32 lo = (u32)f2bf(v[0]) | ((u32)f2bf(v[1]) << 16);
  u32 hi = (u32)f2bf(v[2]) | ((u32)f2bf(v[3]) << 16);
  ((uint2*)xbf)[i] = make_uint2(lo, hi);
}

__global__ void k_fill_t2p(int* t2p) {
  int i = blockIdx.x * 256 + threadIdx.x;
  if (i < CV) t2p[i] = -1;
}
__global__ void k_scatter_t2p(const int* __restrict__ untied, int* __restrict__ t2p) {
  int p = blockIdx.x * 256 + threadIdx.x;
  if (p < CP) t2p[untied[p]] = p;
}
__global__ void k_slots(const int* __restrict__ ids, const int* __restrict__ t2p,
                        int* __restrict__ slots) {
  int i = blockIdx.x * 256 + threadIdx.x;
  if (i < CBL) slots[i] = t2p[ids[i]];
}

// ---------------- bf16 MFMA GEMM: C[m,n] = sum_k A[m,k]*B[n,k] (+epilogue) ----
// A: [M,K] bf16 row-major, B: [N,K] bf16 row-major (i.e. C = A @ B^T).
// 256 threads = 4 waves in 2x2; wave computes 64x64; block 128x128.
enum { EPI_F32B = 0, EPI_RELU2 = 1, EPI_BF = 2, EPI_SCORES = 3, EPI_LOGITS = 4 };

template<int EPI>
__global__ __launch_bounds__(256)
void k_gemm(const bfraw* __restrict__ A, const bfraw* __restrict__ Bw,
            const float* __restrict__ bias, float* __restrict__ Cf,
            bfraw* __restrict__ Cb, int K, int N, float scale,
            long sAz, long sBz, long sCz,
            const int* __restrict__ t2p, const float* __restrict__ tp,
            float* __restrict__ outp)
{
  int bm = blockIdx.x, bn = blockIdx.y, z = blockIdx.z;
  if constexpr (EPI == EPI_SCORES) { if (bn > bm) return; }  // strict-causal block skip
  const bfraw* Ap = A + (long)z * sAz;
  const bfraw* Bp = Bw + (long)z * sBz;
  int wave = threadIdx.x >> 6, lane = threadIdx.x & 63;
  int lr = lane & 15, lk = lane >> 4;
  int r0 = bm * 128 + (wave >> 1) * 64;
  int c0 = bn * 128 + (wave & 1) * 64;

  f32x4 acc[4][4] = {};
  const bfraw* arow[4];
  const bfraw* brow[4];
#pragma unroll
  for (int i = 0; i < 4; i++) arow[i] = Ap + (long)(r0 + i * 16 + lr) * K + lk * 8;
#pragma unroll
  for (int j = 0; j < 4; j++) brow[j] = Bp + (long)(c0 + j * 16 + lr) * K + lk * 8;

  for (int k0 = 0; k0 < K; k0 += 32) {
    bf16x8 af[4], bf_[4];
#pragma unroll
    for (int i = 0; i < 4; i++) af[i] = *(const bf16x8*)(arow[i] + k0);
#pragma unroll
    for (int j = 0; j < 4; j++) bf_[j] = *(const bf16x8*)(brow[j] + k0);
#pragma unroll
    for (int i = 0; i < 4; i++)
#pragma unroll
      for (int j = 0; j < 4; j++)
        acc[i][j] = __builtin_amdgcn_mfma_f32_16x16x32_bf16(af[i], bf_[j], acc[i][j], 0, 0, 0);
  }

#pragma unroll
  for (int j = 0; j < 4; j++) {
    int n = c0 + j * 16 + lr;
    float bias_v = 0.f;
    if constexpr (EPI != EPI_SCORES) bias_v = bias[n];
    int s = 0;
    if constexpr (EPI == EPI_LOGITS) s = t2p[n];
#pragma unroll
    for (int i = 0; i < 4; i++) {
#pragma unroll
      for (int r = 0; r < 4; r++) {
        int m = r0 + i * 16 + lk * 4 + r;
        float v = acc[i][j][r];
        if constexpr (EPI == EPI_F32B) {
          Cf[(long)m * N + n] = v + bias_v;
        } else if constexpr (EPI == EPI_RELU2) {
          float t = fmaxf(v + bias_v, 0.f);
          Cb[(long)m * N + n] = f2bf(t * t);
        } else if constexpr (EPI == EPI_BF) {
          Cb[(long)m * N + n] = f2bf(v + bias_v);
        } else if constexpr (EPI == EPI_SCORES) {
          Cf[sCz * z + (long)m * N + n] = v * scale;
        } else {  // EPI_LOGITS: fold bias + scattered total_partial
          float vv = v + bias_v;
          if (s >= 0) vv += tp[(long)m * CP + s];
          outp[(long)m * CV + n] = vv;
        }
      }
    }
  }
}

// ---------------- persistent GRU ----------------
// 128 WGs x 256 threads. WG wg owns channels j0=wg*8 .. j0+7 (both batches).
// Per step: all-gather h via self-validating u64 messages (f32 bits | tag<<32):
// no fences needed — each datum individually carries its step tag.
// msgq layout: [2 buffers][128 chunks][16 slots] u64; slot s: batch=s>>3, ch=j0+(s&7).
__global__ __launch_bounds__(256)
void k_gru(const float* __restrict__ Whh, const float* __restrict__ bhh,
           const float* __restrict__ xp, float* __restrict__ states,
           bfraw* __restrict__ statesbf, u64* __restrict__ msgq)
{
  __shared__ float wlds[24 * CH];   // 96 KB: 8 channels x {r,z,n}
  __shared__ float hlds[2 * CH];    // 8 KB
  __shared__ float out16[16];
  const int wg = blockIdx.x;        // 0..127
  const int tid = threadIdx.x;      // 0..255
  const int j0 = wg * 8;

  // stage this WG's 24 weight rows into LDS (once); row order r0..7, z0..7, n0..7
  for (int idx = tid; idx < 24 * (CH / 4); idx += 256) {
    int ridx = idx >> 8;            // 256 f32x4 per row
    int kc = idx & 255;
    int g = ridx >> 3, jj = ridx & 7;
    ((f32x4*)wlds)[idx] = ((const f32x4*)(Whh + (long)(g * CH + j0 + jj) * CH))[kc];
  }
  const int jj = tid >> 5, part = tid & 31;   // 8 channels x 32-way K split
  const int chunk = tid >> 1, half = tid & 1; // reader mapping: 2 threads/chunk
  float br = 0, bz = 0, bnn = 0;
  if (part == 0) { br = bhh[j0 + jj]; bz = bhh[CH + j0 + jj]; bnn = bhh[2 * CH + j0 + jj]; }
  __syncthreads();

  for (int t = 0; t < CL; t++) {
    // issue xp loads early (independent of h, hidden under the spin)
    float xr0 = 0, xz0 = 0, xn0 = 0, xr1 = 0, xz1 = 0, xn1 = 0;
    if (part == 0) {
      const float* x0 = xp + (long)t * CH3 + (j0 + jj);
      const float* x1 = xp + (long)(CL + t) * CH3 + (j0 + jj);
      xr0 = x0[0]; xz0 = x0[CH]; xn0 = x0[2 * CH];
      xr1 = x1[0]; xz1 = x1[CH]; xn1 = x1[2 * CH];
    }
    if (t == 0) {
      for (int i = tid; i < 2 * CH; i += 256) hlds[i] = 0.f;
      __syncthreads();
    } else {
      const u32 want = (u32)t;
      u64* base = msgq + ((size_t)(t & 1) * 128 + chunk) * 16 + half * 8;
      float* hdst = hlds + half * CH + chunk * 8;
      bool ok;
      do {
        u64 v[8];
#pragma unroll
        for (int q = 0; q < 8; q++)
          v[q] = __hip_atomic_load(base + q, __ATOMIC_RELAXED, __HIP_MEMORY_SCOPE_AGENT);
        ok = true;
#pragma unroll
        for (int q = 0; q < 8; q++) ok &= ((u32)(v[q] >> 32) == want);
#pragma unroll
        for (int q = 0; q < 8; q++) hdst[q] = __uint_as_float((u32)v[q]);
      } while (!__syncthreads_and((int)ok));
    }

    // 3 dots x 2 batches for channel j0+jj, K split 32 ways
    float ar0 = 0, az0 = 0, an0 = 0, ar1 = 0, az1 = 0, an1 = 0;
    const f32x4* wr = (const f32x4*)(wlds + (0 + jj) * CH);
    const f32x4* wz = (const f32x4*)(wlds + (8 + jj) * CH);
    const f32x4* wn = (const f32x4*)(wlds + (16 + jj) * CH);
    const f32x4* h0 = (const f32x4*)hlds;
    const f32x4* h1 = (const f32x4*)(hlds + CH);
#pragma unroll
    for (int u = 0; u < 8; u++) {
      int k4 = part + 32 * u;
      f32x4 vr = wr[k4], vz = wz[k4], vn = wn[k4];
      f32x4 a0 = h0[k4], a1 = h1[k4];
#pragma unroll
      for (int e = 0; e < 4; e++) {
        ar0 += a0[e] * vr[e]; az0 += a0[e] * vz[e]; an0 += a0[e] * vn[e];
        ar1 += a1[e] * vr[e]; az1 += a1[e] * vz[e]; an1 += a1[e] * vn[e];
      }
    }
#pragma unroll
    for (int d = 1; d < 32; d <<= 1) {
      ar0 += __shfl_xor(ar0, d); az0 += __shfl_xor(az0, d); an0 += __shfl_xor(an0, d);
      ar1 += __shfl_xor(ar1, d); az1 += __shfl_xor(az1, d); an1 += __shfl_xor(an1, d);
    }
    if (part == 0) {
      float hr = ar0 + br, hz = az0 + bz, hn = an0 + bnn;
      float r = 1.f / (1.f + __expf(-(xr0 + hr)));
      float z = 1.f / (1.f + __expf(-(xz0 + hz)));
      float nn = tanhf(xn0 + r * hn);
      float hp = hlds[j0 + jj];
      float hnew0 = (1.f - z) * nn + z * hp;

      hr = ar1 + br; hz = az1 + bz; hn = an1 + bnn;
      float r1 = 1.f / (1.f + __expf(-(xr1 + hr)));
      float z1 = 1.f / (1.f + __expf(-(xz1 + hz)));
      float n1 = tanhf(xn1 + r1 * hn);
      float hp1 = hlds[CH + j0 + jj];
      float hnew1 = (1.f - z1) * n1 + z1 * hp1;

      out16[jj] = hnew0; out16[8 + jj] = hnew1;
      long s0 = (long)t * CH + j0 + jj;
      long s1 = (long)(CL + t) * CH + j0 + jj;
      states[s0] = hnew0;         states[s1] = hnew1;
      statesbf[s0] = f2bf(hnew0); statesbf[s1] = f2bf(hnew1);
    }
    __syncthreads();
    if (tid < 16) {
      u64 v = (u64)__float_as_uint(out16[tid]) | ((u64)(u32)(t + 1) << 32);
      __hip_atomic_store(msgq + ((size_t)((t + 1) & 1) * 128 + wg) * 16 + tid, v,
                         __ATOMIC_RELAXED, __HIP_MEMORY_SCOPE_AGENT);
    }
  }
}

// ---------------- causal softmax + gate + scatter into tp ----------------
__global__ __launch_bounds__(256)
void k_attn(const float* __restrict__ scores, const float* __restrict__ states,
            const float* __restrict__ wgv, const float* __restrict__ bg,
            const float* __restrict__ mscale, const int* __restrict__ slots,
            float* __restrict__ tp)
{
  int row = blockIdx.x;               // b*L + i
  int b = row >> 11, i = row & 2047;
  if (i == 0) return;                 // strict causal: row 0 has no context
  __shared__ float mem[CP];           // 16 KB partial-slot accumulator
  __shared__ float es[CL];            // 8 KB staged scores/exp
  __shared__ float red[4];
  int tid = threadIdx.x;
  for (int p = tid; p < CP; p += 256) mem[p] = 0.f;

  // gate = sigmoid(states[row] . wg + bg)
  float gd = 0.f;
  const float* st = states + (long)row * CH;
  for (int k = tid; k < CH; k += 256) gd += st[k] * wgv[k];

  const float* srow = scores + (long)b * CL * CL + (long)i * CL;
  float mx = -1e30f;
  for (int k = tid; k < i; k += 256) { float v = srow[k]; es[k] = v; mx = fmaxf(mx, v); }

#pragma unroll
  for (int d = 1; d < 64; d <<= 1) { gd += __shfl_xor(gd, d); mx = fmaxf(mx, __shfl_xor(mx, d)); }
  int wv = tid >> 6;
  if ((tid & 63) == 0) red[wv] = mx;
  __syncthreads();
  mx = fmaxf(fmaxf(red[0], red[1]), fmaxf(red[2], red[3]));
  __syncthreads();
  if ((tid & 63) == 0) red[wv] = gd;
  __syncthreads();
  gd = red[0] + red[1] + red[2] + red[3] + bg[0];
  float gate = 1.f / (1.f + __expf(-gd));
  __syncthreads();

  float se = 0.f;
  for (int k = tid; k < i; k += 256) { float e = __expf(es[k] - mx); es[k] = e; se += e; }
#pragma unroll
  for (int d = 1; d < 64; d <<= 1) se += __shfl_xor(se, d);
  if ((tid & 63) == 0) red[wv] = se;
  __syncthreads();
  se = red[0] + red[1] + red[2] + red[3];
  float coef = gate * mscale[0] / fmaxf(se, 1e-6f);
  __syncthreads();

  for (int k = tid; k < i; k += 256) {
    int s = slots[b * CL + k];
    if (s >= 0) atomicAdd(&mem[s], es[k] * coef);
  }
  __syncthreads();
  float* tprow = tp + (long)row * CP;
  for (int p = tid; p < CP; p += 256) tprow[p] += mem[p];
}

// ---------------- launch ----------------
extern "C" void kernel_launch(void* const* d_in, const int* in_sizes, int n_in,
                              void* d_out, int out_size, void* d_ws, size_t ws_size,
                              hipStream_t stream)
{
  const int*   ids    = (const int*)d_in[0];
  const int*   untied = (const int*)d_in[1];
  const float* emb    = (const float*)d_in[2];
  const float* w_ih   = (const float*)d_in[3];
  const float* w_hh   = (const float*)d_in[4];
  const float* b_ih   = (const float*)d_in[5];
  const float* b_hh   = (const float*)d_in[6];
  const float* wq     = (const float*)d_in[7];
  const float* bq     = (const float*)d_in[8];
  const float* wk     = (const float*)d_in[9];
  const float* bk     = (const float*)d_in[10];
  const float* wgv    = (const float*)d_in[11];
  const float* bg     = (const float*)d_in[12];
  const float* w_fc   = (const float*)d_in[13];
  const float* b_fc   = (const float*)d_in[14];
  const float* w_proj = (const float*)d_in[15];
  const float* b_proj = (const float*)d_in[16];
  const float* out_b  = (const float*)d_in[17];
  const float* w_part = (const float*)d_in[18];
  const float* b_part = (const float*)d_in[19];
  const float* mscale = (const float*)d_in[20];
  float* out = (float*)d_out;

  char* ws = (char*)d_ws;
  size_t off = 0;
  auto alloc = [&](size_t bytes) -> char* {
    char* p = ws + off; off += (bytes + 255) & ~(size_t)255; return p;
  };
  bfraw* emb_bf    = (bfraw*)alloc((size_t)CV * CE * 2);      // 32.8 MB
  bfraw* wih_bf    = (bfraw*)alloc((size_t)CH3 * CE * 2);
  bfraw* wfc_bf    = (bfraw*)alloc((size_t)CE4 * CH * 2);
  bfraw* wproj_bf  = (bfraw*)alloc((size_t)CE * CE4 * 2);
  bfraw* wpart_bf  = (bfraw*)alloc((size_t)CP * CE * 2);
  bfraw* wq_bf     = (bfraw*)alloc((size_t)CM * CH * 2);
  bfraw* wk_bf     = (bfraw*)alloc((size_t)CM * CH * 2);
  bfraw* x_bf      = (bfraw*)alloc((size_t)CBL * CE * 2);
  float* xp        = (float*)alloc((size_t)CBL * CH3 * 4);    // 50.3 MB (reused for scores)
  float* states    = (float*)alloc((size_t)CBL * CH * 4);
  bfraw* states_bf = (bfraw*)alloc((size_t)CBL * CH * 2);
  bfraw* head_bf   = (bfraw*)alloc((size_t)CBL * CE4 * 2);
  bfraw* bfeat_bf  = (bfraw*)alloc((size_t)CBL * CE * 2);
  bfraw* q_bf      = (bfraw*)alloc((size_t)CBL * CM * 2);
  bfraw* k_bf      = (bfraw*)alloc((size_t)CBL * CM * 2);
  float* tp        = (float*)alloc((size_t)CBL * CP * 4);     // 67 MB
  int*   t2p       = (int*)alloc((size_t)CV * 4);
  int*   slots     = (int*)alloc((size_t)CBL * 4);
  u64*   msgq      = (u64*)alloc(sizeof(u64) * 2 * 128 * 16); // 32 KB
  float* scores    = xp;   // overlay: xp is dead after k_gru (stream-ordered)
  (void)in_sizes; (void)n_in; (void)out_size; (void)ws_size;

  auto cvt = [&](const float* s, bfraw* d, int n) {
    int n4 = n / 4;
    k_cvt_bf16<<<(n4 + 255) / 256, 256, 0, stream>>>(s, d, n4);
  };
  cvt(emb, emb_bf, CV * CE);
  cvt(w_ih, wih_bf, CH3 * CE);
  cvt(w_fc, wfc_bf, CE4 * CH);
  cvt(w_proj, wproj_bf, CE * CE4);
  cvt(w_part, wpart_bf, CP * CE);
  cvt(wq, wq_bf, CM * CH);
  cvt(wk, wk_bf, CM * CH);
  k_fill_t2p<<<(CV + 255) / 256, 256, 0, stream>>>(t2p);
  k_scatter_t2p<<<CP / 256, 256, 0, stream>>>(untied, t2p);
  k_slots<<<CBL / 256, 256, 0, stream>>>(ids, t2p, slots);
  k_gather_x<<<(CBL * CE / 4) / 256, 256, 0, stream>>>(emb, ids, x_bf);

  // xp = x @ W_ih^T + b_ih   [4096, 3072]
  k_gemm<EPI_F32B><<<dim3(CBL / 128, CH3 / 128), 256, 0, stream>>>(
      x_bf, wih_bf, b_ih, xp, nullptr, CE, CH3, 1.f, 0, 0, 0, nullptr, nullptr, nullptr);

  // sequential GRU (persistent, 128 resident WGs)
  k_gru<<<128, 256, 0, stream>>>(w_hh, b_hh, xp, states, states_bf, msgq);

  // head = relu(states @ w_fc^T + b_fc)^2  -> bf16 [4096, 2048]
  k_gemm<EPI_RELU2><<<dim3(CBL / 128, CE4 / 128), 256, 0, stream>>>(
      states_bf, wfc_bf, b_fc, nullptr, head_bf, CH, CE4, 1.f, 0, 0, 0, nullptr, nullptr, nullptr);
  // base_feat = head @ w_proj^T + b_proj  -> bf16 [4096, 512]
  k_gemm<EPI_BF><<<dim3(CBL / 128, CE / 128), 256, 0, stream>>>(
      head_bf, wproj_bf, b_proj, nullptr, bfeat_bf, CE4, CE, 1.f, 0, 0, 0, nullptr, nullptr, nullptr);
  // q, k projections [4096, 256]
  k_gemm<EPI_BF><<<dim3(CBL / 128, CM / 128), 256, 0, stream>>>(
      states_bf, wq_bf, bq, nullptr, q_bf, CH, CM, 1.f, 0, 0, 0, nullptr, nullptr, nullptr);
  k_gemm<EPI_BF><<<dim3(CBL / 128, CM / 128), 256, 0, stream>>>(
      states_bf, wk_bf, bk, nullptr, k_bf, CH, CM, 1.f, 0, 0, 0, nullptr, nullptr, nullptr);
  // scores[b] = q_b @ k_b^T / 16  [2, 2048, 2048] (lower-triangular blocks only)
  k_gemm<EPI_SCORES><<<dim3(CL / 128, CL / 128, CB), 256, 0, stream>>>(
      q_bf, k_bf, nullptr, scores, nullptr, CM, CL, 0.0625f,
      (long)CL * CM, (long)CL * CM, (long)CL * CL, nullptr, nullptr, nullptr);
  // tp = base_feat @ w_partial^T + b_partial  [4096, 4096] fp32
  k_gemm<EPI_F32B><<<dim3(CBL / 128, CP / 128), 256, 0, stream>>>(
      bfeat_bf, wpart_bf, b_part, tp, nullptr, CE, CP, 1.f, 0, 0, 0, nullptr, nullptr, nullptr);
  // softmax + gate + slot-scatter, accumulate into tp
  k_attn<<<CBL, 256, 0, stream>>>(scores, states, wgv, bg, mscale, slots, tp);
  // logits = base_feat @ emb^T + output_bias, + tp scattered at untied columns
  k_gemm<EPI_LOGITS><<<dim3(CBL / 128, CV / 128), 256, 0, stream>>>(
      bfeat_bf, emb_bf, out_b, nullptr, nullptr, CE, CV, 1.f, 0, 0, 0, t2p, tp, out);
}

// Round 3
// 9850.359 us; speedup vs baseline: 1.0049x; 1.0049x over previous
//
#include <hip/hip_runtime.h>
#include <hip/hip_bf16.h>
#include <math.h>

// Problem constants (B, L, V, E, H, M, P)
#define CB 2
#define CL 2048
#define CV 32000
#define CE 512
#define CH 1024
#define CM 256
#define CP 4096
#define CBL (CB*CL)     // 4096 rows
#define CH3 (3*CH)      // 3072
#define CE4 (4*CE)      // 2048

typedef __bf16 bf16x8 __attribute__((ext_vector_type(8)));
typedef float  f32x4  __attribute__((ext_vector_type(4)));
typedef unsigned short bfraw;
typedef unsigned int   u32;
typedef unsigned long long u64;

__device__ __forceinline__ bfraw f2bf(float f) {
  u32 u = __float_as_uint(f);
  u = (u + 0x7fffu + ((u >> 16) & 1u)) >> 16;   // RNE
  return (bfraw)u;
}

// ---------------- prep kernels ----------------
__global__ void k_cvt_bf16(const float* __restrict__ s, bfraw* __restrict__ d, int n4) {
  int i = blockIdx.x * 256 + threadIdx.x;
  if (i >= n4) return;
  f32x4 v = ((const f32x4*)s)[i];
  u32 lo = (u32)f2bf(v[0]) | ((u32)f2bf(v[1]) << 16);
  u32 hi = (u32)f2bf(v[2]) | ((u32)f2bf(v[3]) << 16);
  ((uint2*)d)[i] = make_uint2(lo, hi);
}

__global__ void k_gather_x(const float* __restrict__ emb, const int* __restrict__ ids,
                           bfraw* __restrict__ xbf) {
  int i = blockIdx.x * 256 + threadIdx.x;     // over CBL*CE/4 = 524288
  int m = i >> 7;                             // CE/4 = 128 float4 per row
  int c = i & 127;
  long src = (long)ids[m] * CE + c * 4;
  f32x4 v = *(const f32x4*)(emb + src);
  u32 lo = (u32)f2bf(v[0]) | ((u32)f2bf(v[1]) << 16);
  u32 hi = (u32)f2bf(v[2]) | ((u32)f2bf(v[3]) << 16);
  ((uint2*)xbf)[i] = make_uint2(lo, hi);
}

__global__ void k_fill_t2p(int* t2p) {
  int i = blockIdx.x * 256 + threadIdx.x;
  if (i < CV) t2p[i] = -1;
}
__global__ void k_scatter_t2p(const int* __restrict__ untied, int* __restrict__ t2p) {
  int p = blockIdx.x * 256 + threadIdx.x;
  if (p < CP) t2p[untied[p]] = p;
}
__global__ void k_slots(const int* __restrict__ ids, const int* __restrict__ t2p,
                        int* __restrict__ slots) {
  int i = blockIdx.x * 256 + threadIdx.x;
  if (i < CBL) slots[i] = t2p[ids[i]];
}

// ---------------- bf16 MFMA GEMM: C[m,n] = sum_k A[m,k]*B[n,k] (+epilogue) ----
// A: [M,K] bf16 row-major, B: [N,K] bf16 row-major (i.e. C = A @ B^T).
// 256 threads = 4 waves in 2x2; wave computes 64x64; block 128x128.
enum { EPI_F32B = 0, EPI_RELU2 = 1, EPI_BF = 2, EPI_SCORES = 3, EPI_LOGITS = 4 };

template<int EPI>
__global__ __launch_bounds__(256)
void k_gemm(const bfraw* __restrict__ A, const bfraw* __restrict__ Bw,
            const float* __restrict__ bias, float* __restrict__ Cf,
            bfraw* __restrict__ Cb, int K, int N, float scale,
            long sAz, long sBz, long sCz,
            const int* __restrict__ t2p, const float* __restrict__ tp,
            float* __restrict__ outp)
{
  int bm = blockIdx.x, bn = blockIdx.y, z = blockIdx.z;
  if constexpr (EPI == EPI_SCORES) { if (bn > bm) return; }  // strict-causal block skip
  const bfraw* Ap = A + (long)z * sAz;
  const bfraw* Bp = Bw + (long)z * sBz;
  int wave = threadIdx.x >> 6, lane = threadIdx.x & 63;
  int lr = lane & 15, lk = lane >> 4;
  int r0 = bm * 128 + (wave >> 1) * 64;
  int c0 = bn * 128 + (wave & 1) * 64;

  f32x4 acc[4][4] = {};
  const bfraw* arow[4];
  const bfraw* brow[4];
#pragma unroll
  for (int i = 0; i < 4; i++) arow[i] = Ap + (long)(r0 + i * 16 + lr) * K + lk * 8;
#pragma unroll
  for (int j = 0; j < 4; j++) brow[j] = Bp + (long)(c0 + j * 16 + lr) * K + lk * 8;

  for (int k0 = 0; k0 < K; k0 += 32) {
    bf16x8 af[4], bf_[4];
#pragma unroll
    for (int i = 0; i < 4; i++) af[i] = *(const bf16x8*)(arow[i] + k0);
#pragma unroll
    for (int j = 0; j < 4; j++) bf_[j] = *(const bf16x8*)(brow[j] + k0);
#pragma unroll
    for (int i = 0; i < 4; i++)
#pragma unroll
      for (int j = 0; j < 4; j++)
        acc[i][j] = __builtin_amdgcn_mfma_f32_16x16x32_bf16(af[i], bf_[j], acc[i][j], 0, 0, 0);
  }

#pragma unroll
  for (int j = 0; j < 4; j++) {
    int n = c0 + j * 16 + lr;
    float bias_v = 0.f;
    if constexpr (EPI != EPI_SCORES) bias_v = bias[n];
    int s = 0;
    if constexpr (EPI == EPI_LOGITS) s = t2p[n];
#pragma unroll
    for (int i = 0; i < 4; i++) {
#pragma unroll
      for (int r = 0; r < 4; r++) {
        int m = r0 + i * 16 + lk * 4 + r;
        float v = acc[i][j][r];
        if constexpr (EPI == EPI_F32B) {
          Cf[(long)m * N + n] = v + bias_v;
        } else if constexpr (EPI == EPI_RELU2) {
          float t = fmaxf(v + bias_v, 0.f);
          Cb[(long)m * N + n] = f2bf(t * t);
        } else if constexpr (EPI == EPI_BF) {
          Cb[(long)m * N + n] = f2bf(v + bias_v);
        } else if constexpr (EPI == EPI_SCORES) {
          Cf[sCz * z + (long)m * N + n] = v * scale;
        } else {  // EPI_LOGITS: fold bias + scattered total_partial
          float vv = v + bias_v;
          if (s >= 0) vv += tp[(long)m * CP + s];
          outp[(long)m * CV + n] = vv;
        }
      }
    }
  }
}

// ---------------- persistent GRU ----------------
// 128 WGs x 256 threads. WG wg owns channels j0=wg*8 .. j0+7 (both batches).
// Weights held in REGISTERS (loop-invariant, 96 VGPR/thread). Per step:
// all-gather h via self-validating u64 messages (f32 bits | tag<<32) with
// per-thread spin (no collective retry); ONE barrier per step (fill->compute);
// hlds double-buffered so fill(t+1) can overlap compute(t).
// Safety of 2-deep msg buffers: a producer stores tag t+2 only after polling
// tag t+1 from ALL WGs, which each stored tag t+1 only after their barrier of
// step t, i.e. after all their lanes finished polling tag t. So no tag t+2
// store can precede any poll of tag t on the same buffer.
__global__ __launch_bounds__(256, 1)
void k_gru(const float* __restrict__ Whh, const float* __restrict__ bhh,
           const float* __restrict__ xp, float* __restrict__ states,
           bfraw* __restrict__ statesbf, u64* __restrict__ msgq)
{
  __shared__ float hlds[2][2 * CH];   // 16 KB double-buffered h
  const int wg = blockIdx.x;          // 0..127
  const int tid = threadIdx.x;        // 0..255
  const int j0 = wg * 8;
  const int jj = tid >> 5, part = tid & 31;   // 8 channels x 32-way K split
  const int chunk = tid >> 1, half = tid & 1; // reader mapping: 2 threads/chunk

  // preload this thread's weight slices into registers (loop-invariant)
  f32x4 wr[8], wz[8], wn[8];
  {
    const f32x4* R = (const f32x4*)(Whh + (long)(0 * CH + j0 + jj) * CH);
    const f32x4* Z = (const f32x4*)(Whh + (long)(1 * CH + j0 + jj) * CH);
    const f32x4* N = (const f32x4*)(Whh + (long)(2 * CH + j0 + jj) * CH);
#pragma unroll
    for (int u = 0; u < 8; u++) {
      wr[u] = R[part + 32 * u];
      wz[u] = Z[part + 32 * u];
      wn[u] = N[part + 32 * u];
    }
  }
  const float br = bhh[j0 + jj], bz = bhh[CH + j0 + jj], bnn = bhh[2 * CH + j0 + jj];
  for (int i = tid; i < 2 * CH; i += 256) hlds[0][i] = 0.f;
  __syncthreads();

  for (int t = 0; t < CL; t++) {
    const int cur = t & 1;
    // xp loads early (independent of h; latency hides under the spin)
    float xr0 = 0, xz0 = 0, xn0 = 0, xr1 = 0, xz1 = 0, xn1 = 0;
    if (part == 0) {
      const float* x0 = xp + (long)t * CH3 + (j0 + jj);
      const float* x1 = xp + (long)(CL + t) * CH3 + (j0 + jj);
      xr0 = x0[0]; xz0 = x0[CH]; xn0 = x0[2 * CH];
      xr1 = x1[0]; xz1 = x1[CH]; xn1 = x1[2 * CH];
    }
    if (t > 0) {
      const u32 want = (u32)t;
      const u64* src = msgq + ((size_t)cur * 128 + chunk) * 16 + half * 8;
      u64 v[8];
      bool ok;
      do {
        ok = true;
#pragma unroll
        for (int q = 0; q < 8; q++)
          v[q] = __hip_atomic_load(src + q, __ATOMIC_RELAXED, __HIP_MEMORY_SCOPE_AGENT);
#pragma unroll
        for (int q = 0; q < 8; q++) ok &= ((u32)(v[q] >> 32) == want);
      } while (!ok);
      float* hdst = hlds[cur] + half * CH + chunk * 8;
#pragma unroll
      for (int q = 0; q < 8; q++) hdst[q] = __uint_as_float((u32)v[q]);
      __syncthreads();   // fill(t) complete -> compute(t); uniform branch (t>0)
    }

    // 3 dots x 2 batches for channel j0+jj, K split 32 ways, weights in regs
    float ar0 = 0, az0 = 0, an0 = 0, ar1 = 0, az1 = 0, an1 = 0;
    const f32x4* h0 = (const f32x4*)(hlds[cur]);
    const f32x4* h1 = (const f32x4*)(hlds[cur] + CH);
#pragma unroll
    for (int u = 0; u < 8; u++) {
      int k4 = part + 32 * u;
      f32x4 a0 = h0[k4], a1 = h1[k4];
#pragma unroll
      for (int e = 0; e < 4; e++) {
        ar0 += a0[e] * wr[u][e]; az0 += a0[e] * wz[u][e]; an0 += a0[e] * wn[u][e];
        ar1 += a1[e] * wr[u][e]; az1 += a1[e] * wz[u][e]; an1 += a1[e] * wn[u][e];
      }
    }
#pragma unroll
    for (int d = 1; d < 32; d <<= 1) {
      ar0 += __shfl_xor(ar0, d); az0 += __shfl_xor(az0, d); an0 += __shfl_xor(an0, d);
      ar1 += __shfl_xor(ar1, d); az1 += __shfl_xor(az1, d); an1 += __shfl_xor(an1, d);
    }
    if (part == 0) {
      float hr = ar0 + br, hz = az0 + bz, hn = an0 + bnn;
      float r = 1.f / (1.f + __expf(-(xr0 + hr)));
      float z = 1.f / (1.f + __expf(-(xz0 + hz)));
      float nn = tanhf(xn0 + r * hn);
      float hp = hlds[cur][j0 + jj];
      float hnew0 = (1.f - z) * nn + z * hp;

      hr = ar1 + br; hz = az1 + bz; hn = an1 + bnn;
      float r1 = 1.f / (1.f + __expf(-(xr1 + hr)));
      float z1 = 1.f / (1.f + __expf(-(xz1 + hz)));
      float n1 = tanhf(xn1 + r1 * hn);
      float hp1 = hlds[cur][CH + j0 + jj];
      float hnew1 = (1.f - z1) * n1 + z1 * hp1;

      // message store FIRST (critical path), then bulk state stores
      u64* dst = msgq + ((size_t)((t + 1) & 1) * 128 + wg) * 16;
      u64 m0 = (u64)__float_as_uint(hnew0) | ((u64)(u32)(t + 1) << 32);
      u64 m1 = (u64)__float_as_uint(hnew1) | ((u64)(u32)(t + 1) << 32);
      __hip_atomic_store(dst + jj, m0, __ATOMIC_RELAXED, __HIP_MEMORY_SCOPE_AGENT);
      __hip_atomic_store(dst + 8 + jj, m1, __ATOMIC_RELAXED, __HIP_MEMORY_SCOPE_AGENT);

      long s0 = (long)t * CH + j0 + jj;
      long s1 = (long)(CL + t) * CH + j0 + jj;
      states[s0] = hnew0;         states[s1] = hnew1;
      statesbf[s0] = f2bf(hnew0); statesbf[s1] = f2bf(hnew1);
    }
  }
}

// ---------------- causal softmax + gate + scatter into tp ----------------
__global__ __launch_bounds__(256)
void k_attn(const float* __restrict__ scores, const float* __restrict__ states,
            const float* __restrict__ wgv, const float* __restrict__ bg,
            const float* __restrict__ mscale, const int* __restrict__ slots,
            float* __restrict__ tp)
{
  int row = blockIdx.x;               // b*L + i
  int b = row >> 11, i = row & 2047;
  if (i == 0) return;                 // strict causal: row 0 has no context
  __shared__ float mem[CP];           // 16 KB partial-slot accumulator
  __shared__ float es[CL];            // 8 KB staged scores/exp
  __shared__ float red[4];
  int tid = threadIdx.x;
  for (int p = tid; p < CP; p += 256) mem[p] = 0.f;

  // gate = sigmoid(states[row] . wg + bg)
  float gd = 0.f;
  const float* st = states + (long)row * CH;
  for (int k = tid; k < CH; k += 256) gd += st[k] * wgv[k];

  const float* srow = scores + (long)b * CL * CL + (long)i * CL;
  float mx = -1e30f;
  for (int k = tid; k < i; k += 256) { float v = srow[k]; es[k] = v; mx = fmaxf(mx, v); }

#pragma unroll
  for (int d = 1; d < 64; d <<= 1) { gd += __shfl_xor(gd, d); mx = fmaxf(mx, __shfl_xor(mx, d)); }
  int wv = tid >> 6;
  if ((tid & 63) == 0) red[wv] = mx;
  __syncthreads();
  mx = fmaxf(fmaxf(red[0], red[1]), fmaxf(red[2], red[3]));
  __syncthreads();
  if ((tid & 63) == 0) red[wv] = gd;
  __syncthreads();
  gd = red[0] + red[1] + red[2] + red[3] + bg[0];
  float gate = 1.f / (1.f + __expf(-gd));
  __syncthreads();

  float se = 0.f;
  for (int k = tid; k < i; k += 256) { float e = __expf(es[k] - mx); es[k] = e; se += e; }
#pragma unroll
  for (int d = 1; d < 64; d <<= 1) se += __shfl_xor(se, d);
  if ((tid & 63) == 0) red[wv] = se;
  __syncthreads();
  se = red[0] + red[1] + red[2] + red[3];
  float coef = gate * mscale[0] / fmaxf(se, 1e-6f);
  __syncthreads();

  for (int k = tid; k < i; k += 256) {
    int s = slots[b * CL + k];
    if (s >= 0) atomicAdd(&mem[s], es[k] * coef);
  }
  __syncthreads();
  float* tprow = tp + (long)row * CP;
  for (int p = tid; p < CP; p += 256) tprow[p] += mem[p];
}

// ---------------- launch ----------------
extern "C" void kernel_launch(void* const* d_in, const int* in_sizes, int n_in,
                              void* d_out, int out_size, void* d_ws, size_t ws_size,
                              hipStream_t stream)
{
  const int*   ids    = (const int*)d_in[0];
  const int*   untied = (const int*)d_in[1];
  const float* emb    = (const float*)d_in[2];
  const float* w_ih   = (const float*)d_in[3];
  const float* w_hh   = (const float*)d_in[4];
  const float* b_ih   = (const float*)d_in[5];
  const float* b_hh   = (const float*)d_in[6];
  const float* wq     = (const float*)d_in[7];
  const float* bq     = (const float*)d_in[8];
  const float* wk     = (const float*)d_in[9];
  const float* bk     = (const float*)d_in[10];
  const float* wgv    = (const float*)d_in[11];
  const float* bg     = (const float*)d_in[12];
  const float* w_fc   = (const float*)d_in[13];
  const float* b_fc   = (const float*)d_in[14];
  const float* w_proj = (const float*)d_in[15];
  const float* b_proj = (const float*)d_in[16];
  const float* out_b  = (const float*)d_in[17];
  const float* w_part = (const float*)d_in[18];
  const float* b_part = (const float*)d_in[19];
  const float* mscale = (const float*)d_in[20];
  float* out = (float*)d_out;

  char* ws = (char*)d_ws;
  size_t off = 0;
  auto alloc = [&](size_t bytes) -> char* {
    char* p = ws + off; off += (bytes + 255) & ~(size_t)255; return p;
  };
  bfraw* emb_bf    = (bfraw*)alloc((size_t)CV * CE * 2);      // 32.8 MB
  bfraw* wih_bf    = (bfraw*)alloc((size_t)CH3 * CE * 2);
  bfraw* wfc_bf    = (bfraw*)alloc((size_t)CE4 * CH * 2);
  bfraw* wproj_bf  = (bfraw*)alloc((size_t)CE * CE4 * 2);
  bfraw* wpart_bf  = (bfraw*)alloc((size_t)CP * CE * 2);
  bfraw* wq_bf     = (bfraw*)alloc((size_t)CM * CH * 2);
  bfraw* wk_bf     = (bfraw*)alloc((size_t)CM * CH * 2);
  bfraw* x_bf      = (bfraw*)alloc((size_t)CBL * CE * 2);
  float* xp        = (float*)alloc((size_t)CBL * CH3 * 4);    // 50.3 MB (reused for scores)
  float* states    = (float*)alloc((size_t)CBL * CH * 4);
  bfraw* states_bf = (bfraw*)alloc((size_t)CBL * CH * 2);
  bfraw* head_bf   = (bfraw*)alloc((size_t)CBL * CE4 * 2);
  bfraw* bfeat_bf  = (bfraw*)alloc((size_t)CBL * CE * 2);
  bfraw* q_bf      = (bfraw*)alloc((size_t)CBL * CM * 2);
  bfraw* k_bf      = (bfraw*)alloc((size_t)CBL * CM * 2);
  float* tp        = (float*)alloc((size_t)CBL * CP * 4);     // 67 MB
  int*   t2p       = (int*)alloc((size_t)CV * 4);
  int*   slots     = (int*)alloc((size_t)CBL * 4);
  u64*   msgq      = (u64*)alloc(sizeof(u64) * 2 * 128 * 16); // 32 KB
  float* scores    = xp;   // overlay: xp is dead after k_gru (stream-ordered)
  (void)in_sizes; (void)n_in; (void)out_size; (void)ws_size;

  auto cvt = [&](const float* s, bfraw* d, int n) {
    int n4 = n / 4;
    k_cvt_bf16<<<(n4 + 255) / 256, 256, 0, stream>>>(s, d, n4);
  };
  cvt(emb, emb_bf, CV * CE);
  cvt(w_ih, wih_bf, CH3 * CE);
  cvt(w_fc, wfc_bf, CE4 * CH);
  cvt(w_proj, wproj_bf, CE * CE4);
  cvt(w_part, wpart_bf, CP * CE);
  cvt(wq, wq_bf, CM * CH);
  cvt(wk, wk_bf, CM * CH);
  k_fill_t2p<<<(CV + 255) / 256, 256, 0, stream>>>(t2p);
  k_scatter_t2p<<<CP / 256, 256, 0, stream>>>(untied, t2p);
  k_slots<<<CBL / 256, 256, 0, stream>>>(ids, t2p, slots);
  k_gather_x<<<(CBL * CE / 4) / 256, 256, 0, stream>>>(emb, ids, x_bf);

  // xp = x @ W_ih^T + b_ih   [4096, 3072]
  k_gemm<EPI_F32B><<<dim3(CBL / 128, CH3 / 128), 256, 0, stream>>>(
      x_bf, wih_bf, b_ih, xp, nullptr, CE, CH3, 1.f, 0, 0, 0, nullptr, nullptr, nullptr);

  // sequential GRU (persistent, 128 resident WGs)
  k_gru<<<128, 256, 0, stream>>>(w_hh, b_hh, xp, states, states_bf, msgq);

  // head = relu(states @ w_fc^T + b_fc)^2  -> bf16 [4096, 2048]
  k_gemm<EPI_RELU2><<<dim3(CBL / 128, CE4 / 128), 256, 0, stream>>>(
      states_bf, wfc_bf, b_fc, nullptr, head_bf, CH, CE4, 1.f, 0, 0, 0, nullptr, nullptr, nullptr);
  // base_feat = head @ w_proj^T + b_proj  -> bf16 [4096, 512]
  k_gemm<EPI_BF><<<dim3(CBL / 128, CE / 128), 256, 0, stream>>>(
      head_bf, wproj_bf, b_proj, nullptr, bfeat_bf, CE4, CE, 1.f, 0, 0, 0, nullptr, nullptr, nullptr);
  // q, k projections [4096, 256]
  k_gemm<EPI_BF><<<dim3(CBL / 128, CM / 128), 256, 0, stream>>>(
      states_bf, wq_bf, bq, nullptr, q_bf, CH, CM, 1.f, 0, 0, 0, nullptr, nullptr, nullptr);
  k_gemm<EPI_BF><<<dim3(CBL / 128, CM / 128), 256, 0, stream>>>(
      states_bf, wk_bf, bk, nullptr, k_bf, CH, CM, 1.f, 0, 0, 0, nullptr, nullptr, nullptr);
  // scores[b] = q_b @ k_b^T / 16  [2, 2048, 2048] (lower-triangular blocks only)
  k_gemm<EPI_SCORES><<<dim3(CL / 128, CL / 128, CB), 256, 0, stream>>>(
      q_bf, k_bf, nullptr, scores, nullptr, CM, CL, 0.0625f,
      (long)CL * CM, (long)CL * CM, (long)CL * CL, nullptr, nullptr, nullptr);
  // tp = base_feat @ w_partial^T + b_partial  [4096, 4096] fp32
  k_gemm<EPI_F32B><<<dim3(CBL / 128, CP / 128), 256, 0, stream>>>(
      bfeat_bf, wpart_bf, b_part, tp, nullptr, CE, CP, 1.f, 0, 0, 0, nullptr, nullptr, nullptr);
  // softmax + gate + slot-scatter, accumulate into tp
  k_attn<<<CBL, 256, 0, stream>>>(scores, states, wgv, bg, mscale, slots, tp);
  // logits = base_feat @ emb^T + output_bias, + tp scattered at untied columns
  k_gemm<EPI_LOGITS><<<dim3(CBL / 128, CV / 128), 256, 0, stream>>>(
      bfeat_bf, emb_bf, out_b, nullptr, nullptr, CE, CV, 1.f, 0, 0, 0, t2p, tp, out);
}